// Round 9
// baseline (153.172 us; speedup 1.0000x reference)
//
#include <hip/hip_runtime.h>
#include <math.h>

// Problem constants (fixed by reference setup_inputs)
#define NN 8192
#define SS 32
#define DD 32
#define KK 1024
#define OUT_ELEMS ((size_t)NN * SS * DD)   // 8388608; loss scalar at out[OUT_ELEMS]

// loss = S * (1 + BETA) * sum_sq / (N*S*D)
#define LOSS_SCALE (32.0f * 1.001f / 8388608.0f)

typedef _Float16 half8 __attribute__((ext_vector_type(8)));
typedef float   floatx4 __attribute__((ext_vector_type(4)));

#define TILES   (KK / 16)             // 64 k-tiles of 16
#define RG 2                          // 16-row groups per wave -> 32 rows/wave
#define NBLOCKS ((NN / 128) * SS)     // 2048 main blocks

// SESSION NOTES:
//  R6: same-address atomicAdd tail was the hidden floor R1-R6 (~14ns each,
//      serialized) -> per-block partials + tiny reduce kernel.
//  R7: VALUBusy 57% dominated by per-block re-conversion of W (64x redundant
//      per s) + 32 barrier drains -> R8 hoists conversion to a prep kernel
//      writing fragment-major wh/wl; main k-loop has no barriers at all.
//
// Workspace: wh (2 MB) | wl (2 MB) | w2 (128 KB) | part (8 KB)
// Fragment-major: slot g = ((s*64 + tile)*64 + lane); 8 f16 at wh[g*8].
// Lane's B-fragment for (s,tile): W[k=tile*16+(lane&15)][d=(lane>>4)*8 ..+7].

__global__ __launch_bounds__(256) void vq_prep(const float* __restrict__ W,
                                               _Float16* __restrict__ wh,
                                               _Float16* __restrict__ wl,
                                               float* __restrict__ w2) {
    const int g    = blockIdx.x * 256 + threadIdx.x;   // [s:5][tile:6][lane:6]
    const int l    = g & 63;
    const int t    = (g >> 6) & 63;
    const int s    = g >> 12;
    const int col  = l & 15;
    const int quad = l >> 4;
    const int k    = t * 16 + col;

    const float* src = W + ((size_t)s * KK + k) * DD + quad * 8;
    const float4 a = ((const float4*)src)[0];
    const float4 b = ((const float4*)src)[1];
    const float v8[8] = {a.x, a.y, a.z, a.w, b.x, b.y, b.z, b.w};

    float ps = 0.0f;
    half8 h8, l8;
    #pragma unroll
    for (int j = 0; j < 8; ++j) {
        const float v = v8[j];
        ps = fmaf(v, v, ps);
        const _Float16 h = (_Float16)v;
        h8[j] = h;
        l8[j] = (_Float16)(v - (float)h);
    }
    // 4 lanes (quads) share row k: lanes l, l^16, l^32, l^48
    ps += __shfl_xor(ps, 16, 64);
    ps += __shfl_xor(ps, 32, 64);
    if (quad == 0) w2[(size_t)s * KK + k] = ps;

    *(half8*)(wh + (size_t)g * 8) = h8;
    *(half8*)(wl + (size_t)g * 8) = l8;
}

// Main: block = 4 waves, one s, 128 n-rows. Grid 2048. K-loop: per tile,
// 2 global dwordx4 B-loads (L1/L2-hit, 2-deep pipeline), 1 ds_read (w2),
// 6 split-MFMAs, per-slot argmin. No syncthreads in the loop.
__global__ __launch_bounds__(256, 4) void vq_main(const float* __restrict__ z,
                                                  const float* __restrict__ W,
                                                  const _Float16* __restrict__ wh,
                                                  const _Float16* __restrict__ wl,
                                                  const float* __restrict__ w2,
                                                  float* __restrict__ out,
                                                  float* __restrict__ part) {
    __shared__ float lds_w2[KK];      // 4 KB
    __shared__ int   lds_idx[4][32];
    __shared__ float lds_part[4];

    const int s    = blockIdx.x & (SS - 1);
    const int n0b  = (blockIdx.x >> 5) * 128;
    const int tid  = threadIdx.x;
    const int wv   = tid >> 6;
    const int lane = tid & 63;
    const int col  = lane & 15;
    const int quad = lane >> 4;

    const float* __restrict__ Ws = W + (size_t)s * KK * DD;
    const int n0w = n0b + wv * 32;

    // w2[s,:] -> LDS once (broadcast reads in the k-loop are conflict-free)
    const float* w2s = w2 + (size_t)s * KK;
    #pragma unroll
    for (int j = 0; j < 4; ++j) lds_w2[tid + j * 256] = w2s[tid + j * 256];
    __syncthreads();

    // ---- A-fragments: (-2*z) split into f16 hi/lo. A[m=col][d=quad*8+j]. ----
    half8 zh[RG], zl[RG];
    #pragma unroll
    for (int rg = 0; rg < RG; ++rg) {
        const float* zp = z + (size_t)(n0w + rg * 16 + col) * (SS * DD) + s * DD + quad * 8;
        const float4 va = ((const float4*)zp)[0];
        const float4 vb = ((const float4*)zp)[1];
        const float src[8] = {va.x, va.y, va.z, va.w, vb.x, vb.y, vb.z, vb.w};
        #pragma unroll
        for (int j = 0; j < 8; ++j) {
            const float v = -2.0f * src[j];
            const _Float16 h = (_Float16)v;
            zh[rg][j] = h;
            zl[rg][j] = (_Float16)(v - (float)h);
        }
    }

    // B-fragment pointers (fragment-major): per-lane base + 512 f16/tile
    const _Float16* __restrict__ bhp = wh + (size_t)s * (TILES * 64 * 8) + (size_t)lane * 8;
    const _Float16* __restrict__ blp = wl + (size_t)s * (TILES * 64 * 8) + (size_t)lane * 8;

    floatx4 best[RG];
    int bi[RG][4];
    #pragma unroll
    for (int rg = 0; rg < RG; ++rg) {
        best[rg] = (floatx4){INFINITY, INFINITY, INFINITY, INFINITY};
        bi[rg][0] = bi[rg][1] = bi[rg][2] = bi[rg][3] = 0;
    }

    // ---- software pipeline: 2 tiles in regs, next 2 in flight ----
    half8 bhA = *(const half8*)(bhp);
    half8 blA = *(const half8*)(blp);
    half8 bhB = *(const half8*)(bhp + 512);
    half8 blB = *(const half8*)(blp + 512);

    for (int t2 = 0; t2 < TILES / 2; ++t2) {
        half8 nhA, nlA, nhB, nlB;
        const bool more = (t2 + 1 < TILES / 2);
        if (more) {
            const size_t o = (size_t)(2 * t2 + 2) * 512;
            nhA = *(const half8*)(bhp + o);
            nlA = *(const half8*)(blp + o);
            nhB = *(const half8*)(bhp + o + 512);
            nlB = *(const half8*)(blp + o + 512);
        }
        #pragma unroll
        for (int half = 0; half < 2; ++half) {
            const int t = 2 * t2 + half;
            const half8 bh = half ? bhB : bhA;
            const half8 bl = half ? blB : blA;
            const float wv2 = lds_w2[t * 16 + col];
            const floatx4 c0 = {wv2, wv2, wv2, wv2};
            #pragma unroll
            for (int rg = 0; rg < RG; ++rg) {
                floatx4 acc = __builtin_amdgcn_mfma_f32_16x16x32_f16(zh[rg], bh, c0, 0, 0, 0);
                acc = __builtin_amdgcn_mfma_f32_16x16x32_f16(zl[rg], bh, acc, 0, 0, 0);
                acc = __builtin_amdgcn_mfma_f32_16x16x32_f16(zh[rg], bl, acc, 0, 0, 0);
                #pragma unroll
                for (int i = 0; i < 4; ++i) {
                    if (acc[i] < best[rg][i]) { best[rg][i] = acc[i]; bi[rg][i] = t; }  // strict <
                }
            }
        }
        if (more) { bhA = nhA; blA = nlA; bhB = nhB; blB = nlB; }
    }

    // ---- cross-lane argmin over the 16 k-columns; lower k wins ties ----
    #pragma unroll
    for (int rg = 0; rg < RG; ++rg) {
        #pragma unroll
        for (int i = 0; i < 4; ++i) {
            float v = best[rg][i];
            int   k = bi[rg][i] * 16 + col;
            #pragma unroll
            for (int m = 1; m < 16; m <<= 1) {
                const float vo = __shfl_xor(v, m, 64);
                const int   ko = __shfl_xor(k, m, 64);
                if (vo < v || (vo == v && ko < k)) { v = vo; k = ko; }
            }
            if (col == 0) lds_idx[wv][rg * 16 + quad * 4 + i] = k;  // row-in-wave
        }
    }
    __syncthreads();

    // ---- epilogue: 2 lanes per n-row (16 floats each); zq = fp32 W[s,k*] ----
    const int r  = lane & 31;
    const int dh = (lane >> 5) * 16;
    const int krow = lds_idx[wv][r];
    const float* wsrc = Ws + (size_t)krow * DD + dh;
    const size_t zoff = (size_t)(n0w + r) * (SS * DD) + s * DD + dh;
    const float* zsrc = z + zoff;
    float* od = out + zoff;
    float sq = 0.0f;
    #pragma unroll
    for (int cc = 0; cc < 4; ++cc) {
        const float4 wq = ((const float4*)wsrc)[cc];
        const float4 zv = ((const float4*)zsrc)[cc];
        const float d0 = wq.x - zv.x, d1 = wq.y - zv.y;
        const float d2 = wq.z - zv.z, d3 = wq.w - zv.w;
        sq = fmaf(d0, d0, sq); sq = fmaf(d1, d1, sq);
        sq = fmaf(d2, d2, sq); sq = fmaf(d3, d3, sq);
        ((float4*)od)[cc] = wq;
    }
    #pragma unroll
    for (int off = 32; off > 0; off >>= 1) sq += __shfl_down(sq, off, 64);

    // per-block partial -> distinct address; NO same-address atomics
    if (lane == 0) lds_part[wv] = sq;
    __syncthreads();
    if (tid == 0)
        part[blockIdx.x] = lds_part[0] + lds_part[1] + lds_part[2] + lds_part[3];
}

// Tiny final reduce: 1 block sums the 2048 per-block partials.
__global__ __launch_bounds__(256) void vq_loss(const float* __restrict__ part,
                                               float* __restrict__ out) {
    __shared__ float l[4];
    const int tid = threadIdx.x;
    float sum = 0.0f;
    #pragma unroll
    for (int i = 0; i < NBLOCKS / 256; ++i) sum += part[tid + i * 256];
    #pragma unroll
    for (int off = 32; off > 0; off >>= 1) sum += __shfl_down(sum, off, 64);
    if ((tid & 63) == 0) l[tid >> 6] = sum;
    __syncthreads();
    if (tid == 0) out[OUT_ELEMS] = (l[0] + l[1] + l[2] + l[3]) * LOSS_SCALE;
}

extern "C" void kernel_launch(void* const* d_in, const int* in_sizes, int n_in,
                              void* d_out, int out_size, void* d_ws, size_t ws_size,
                              hipStream_t stream) {
    const float* z = (const float*)d_in[0];   // (8192, 1024) fp32
    const float* W = (const float*)d_in[1];   // (32, 1024, 32) fp32
    float* out = (float*)d_out;               // 8388608 zq_st + 1 loss

    _Float16* wh = (_Float16*)d_ws;                       // 2 MB
    _Float16* wl = wh + (size_t)SS * KK * DD;             // 2 MB
    float*    w2 = (float*)(wl + (size_t)SS * KK * DD);   // 128 KB
    float*    part = w2 + (size_t)SS * KK;                // 8 KB

    vq_prep<<<dim3((SS * KK * 4) / 256), dim3(256), 0, stream>>>(W, wh, wl, w2);
    vq_main<<<dim3(NBLOCKS), dim3(256), 0, stream>>>(z, W, wh, wl, w2, out, part);
    vq_loss<<<dim3(1), dim3(256), 0, stream>>>(part, out);
}